// Round 1
// baseline (414.447 us; speedup 1.0000x reference)
//
#include <hip/hip_runtime.h>

// ---------------------------------------------------------------------------
// EdgeModel: out = LayerNorm(LReLU(LReLU(LReLU(X@W1+b1)@W2+b2)@W3+b3))
// X = concat[src, dest, edge_attr, u[batch]]  (E=400000, 512 features)
// Strategy: bf16 MFMA (16x16x32), weights pre-packed to B-frag order in d_ws,
// per-block tile of 128 edges, activations ping-ponged through swizzled LDS.
// ---------------------------------------------------------------------------

typedef short bf16x8 __attribute__((ext_vector_type(8)));   // 8 bf16 (guide §3)
typedef float f32x4 __attribute__((ext_vector_type(4)));
typedef unsigned short us4 __attribute__((ext_vector_type(4)));

__device__ __forceinline__ unsigned short f2bf(float f) {  // RNE f32->bf16
    union { float f; unsigned u; } v; v.f = f;
    return (unsigned short)((v.u + 0x7fffu + ((v.u >> 16) & 1u)) >> 16);
}
__device__ __forceinline__ float lrelu(float v) { return v >= 0.f ? v : 0.01f * v; }

// ---------------------------------------------------------------------------
// Pack W (K x N, row-major f32) into bf16 MFMA-B-fragment order:
// frag(fk,fn): lane l, elem j  ->  W[fk*32 + (l>>4)*8 + j][fn*16 + (l&15)]
// offset(elems) = ((fk*nfn + fn)*64 + l)*8 + j
// Layout in ws: W1p @0 (131072 el), W2p @131072 (65536 el), W3p @196608 (32768 el)
// ---------------------------------------------------------------------------
__global__ void prep_pack(const float* __restrict__ W1, const float* __restrict__ W2,
                          const float* __restrict__ W3, unsigned short* __restrict__ P) {
    int idx = blockIdx.x * 256 + threadIdx.x;
    const float* W; int N, base;
    if (idx < 131072)      { W = W1; N = 256; base = 0; }
    else if (idx < 196608) { W = W2; N = 256; base = 131072; }
    else if (idx < 229376) { W = W3; N = 128; base = 196608; }
    else return;
    int t = idx - base;
    int j = t & 7, l = (t >> 3) & 63, f = t >> 9;
    int nfn = N >> 4;
    int fk = f / nfn, fn = f - fk * nfn;
    int k = fk * 32 + ((l >> 4) << 3) + j;
    int c = fn * 16 + (l & 15);
    P[idx] = f2bf(W[k * N + c]);
}

// ---------------------------------------------------------------------------
// Main fused kernel. Block = 512 threads (8 waves as 2M x 4N), M_TILE = 128.
// ---------------------------------------------------------------------------
__global__ __launch_bounds__(512) void edge_mlp(
    const float* __restrict__ src, const float* __restrict__ dst,
    const float* __restrict__ ea,  const float* __restrict__ u,
    const int* __restrict__ batch, const unsigned short* __restrict__ Wp,
    const float* __restrict__ b1,  const float* __restrict__ b2,
    const float* __restrict__ b3,  const float* __restrict__ gamma,
    const float* __restrict__ beta, float* __restrict__ out, int E)
{
    // xs: 128 rows x 64 bf16 K-slice of X       (16 KB, XOR-swizzled)
    // hs: 128 rows x 256 bf16 activations       (64 KB, XOR-swizzled)
    //     reused as 128 x 128 f32 for LayerNorm
    __shared__ __align__(16) unsigned char xs[128 * 128];
    __shared__ __align__(16) unsigned char hs[128 * 512];

    const int tid  = threadIdx.x;
    const int lane = tid & 63;
    const int w    = tid >> 6;          // wave 0..7
    const int wm   = w >> 2;            // 0..1  (M half: rows wm*64..+64)
    const int wn   = w & 3;             // 0..3  (N quarter)
    const int l15  = lane & 15;
    const int lhi  = lane >> 4;         // 0..3
    const int m0   = blockIdx.x * 128;

    const unsigned short* W1p = Wp;
    const unsigned short* W2p = Wp + 131072;
    const unsigned short* W3p = Wp + 196608;

    const f32x4 zero4 = {0.f, 0.f, 0.f, 0.f};
    f32x4 acc[4][4];
    #pragma unroll
    for (int m = 0; m < 4; ++m)
        #pragma unroll
        for (int n = 0; n < 4; ++n) acc[m][n] = zero4;

    // ============================ layer 1 (K=512) ===========================
    for (int ks = 0; ks < 8; ++ks) {
        __syncthreads();
        {   // stage 128x64 f32 slice of concat-X as bf16 into xs (swizzled)
            const int fb  = ks << 6;          // global feature base
            const int seg = fb >> 7;          // 0:src 1:dst 2:ea 3:u[batch]
            const int sc  = fb & 127;         // 0 or 64
            const float* bp = (seg == 0) ? src : (seg == 1) ? dst : ea;
            #pragma unroll
            for (int p = 0; p < 4; ++p) {
                int r  = p * 32 + (tid >> 4); // 0..127
                int c4 = tid & 15;            // float4 index in 64-col slice
                int rg = m0 + r; rg = rg < E ? rg : E - 1;
                const float* gp = (seg == 3)
                    ? u  + (size_t)batch[rg] * 128 + sc + c4 * 4
                    : bp + (size_t)rg       * 128 + sc + c4 * 4;
                f32x4 v = *reinterpret_cast<const f32x4*>(gp);
                us4 h; h.x = f2bf(v.x); h.y = f2bf(v.y); h.z = f2bf(v.z); h.w = f2bf(v.w);
                int bo = r * 128 + ((c4 * 8) ^ ((r & 7) << 4));
                *reinterpret_cast<us4*>(&xs[bo]) = h;
            }
        }
        __syncthreads();
        #pragma unroll
        for (int kk = 0; kk < 2; ++kk) {       // two K=32 steps per slice
            const int klo = kk * 32 + lhi * 8; // k within slice
            bf16x8 a[4], b[4];
            #pragma unroll
            for (int m = 0; m < 4; ++m) {
                int r = wm * 64 + m * 16 + l15;
                a[m] = *reinterpret_cast<const bf16x8*>(
                    &xs[r * 128 + ((klo * 2) ^ ((r & 7) << 4))]);
            }
            const int fk = ks * 2 + kk;
            #pragma unroll
            for (int n = 0; n < 4; ++n) {
                int fn = wn * 4 + n;
                b[n] = *reinterpret_cast<const bf16x8*>(
                    W1p + (((fk * 16 + fn) << 6) + lane) * 8);
            }
            #pragma unroll
            for (int m = 0; m < 4; ++m)
                #pragma unroll
                for (int n = 0; n < 4; ++n)
                    acc[m][n] = __builtin_amdgcn_mfma_f32_16x16x32_bf16(
                        a[m], b[n], acc[m][n], 0, 0, 0);
        }
    }
    // h1 = LReLU(acc + b1) -> hs (bf16, swizzled). hs untouched so far: no barrier.
    #pragma unroll
    for (int n = 0; n < 4; ++n) {
        int col = wn * 64 + n * 16 + l15;
        float bias = b1[col];
        #pragma unroll
        for (int m = 0; m < 4; ++m)
            #pragma unroll
            for (int r = 0; r < 4; ++r) {
                int row = wm * 64 + m * 16 + lhi * 4 + r;
                float v = lrelu(acc[m][n][r] + bias);
                *reinterpret_cast<unsigned short*>(
                    &hs[row * 512 + ((col * 2) ^ ((row & 7) << 4))]) = f2bf(v);
            }
    }
    __syncthreads();

    // ============================ layer 2 (K=256) ===========================
    #pragma unroll
    for (int m = 0; m < 4; ++m)
        #pragma unroll
        for (int n = 0; n < 4; ++n) acc[m][n] = zero4;
    for (int kk = 0; kk < 8; ++kk) {
        const int k = kk * 32 + lhi * 8;
        bf16x8 a[4], b[4];
        #pragma unroll
        for (int m = 0; m < 4; ++m) {
            int r = wm * 64 + m * 16 + l15;
            a[m] = *reinterpret_cast<const bf16x8*>(
                &hs[r * 512 + ((k * 2) ^ ((r & 7) << 4))]);
        }
        #pragma unroll
        for (int n = 0; n < 4; ++n) {
            int fn = wn * 4 + n;
            b[n] = *reinterpret_cast<const bf16x8*>(
                W2p + (((kk * 16 + fn) << 6) + lane) * 8);
        }
        #pragma unroll
        for (int m = 0; m < 4; ++m)
            #pragma unroll
            for (int n = 0; n < 4; ++n)
                acc[m][n] = __builtin_amdgcn_mfma_f32_16x16x32_bf16(
                    a[m], b[n], acc[m][n], 0, 0, 0);
    }
    __syncthreads();   // everyone done READING h1 before overwrite
    #pragma unroll
    for (int n = 0; n < 4; ++n) {
        int col = wn * 64 + n * 16 + l15;
        float bias = b2[col];
        #pragma unroll
        for (int m = 0; m < 4; ++m)
            #pragma unroll
            for (int r = 0; r < 4; ++r) {
                int row = wm * 64 + m * 16 + lhi * 4 + r;
                float v = lrelu(acc[m][n][r] + bias);
                *reinterpret_cast<unsigned short*>(
                    &hs[row * 512 + ((col * 2) ^ ((row & 7) << 4))]) = f2bf(v);
            }
    }
    __syncthreads();

    // ============================ layer 3 (K=256, N=128) ====================
    f32x4 acc3[4][2];
    #pragma unroll
    for (int m = 0; m < 4; ++m) { acc3[m][0] = zero4; acc3[m][1] = zero4; }
    for (int kk = 0; kk < 8; ++kk) {
        const int k = kk * 32 + lhi * 8;
        bf16x8 a[4], b[2];
        #pragma unroll
        for (int m = 0; m < 4; ++m) {
            int r = wm * 64 + m * 16 + l15;
            a[m] = *reinterpret_cast<const bf16x8*>(
                &hs[r * 512 + ((k * 2) ^ ((r & 7) << 4))]);
        }
        #pragma unroll
        for (int n = 0; n < 2; ++n) {
            int fn = wn * 2 + n;
            b[n] = *reinterpret_cast<const bf16x8*>(
                W3p + (((kk * 8 + fn) << 6) + lane) * 8);
        }
        #pragma unroll
        for (int m = 0; m < 4; ++m)
            #pragma unroll
            for (int n = 0; n < 2; ++n)
                acc3[m][n] = __builtin_amdgcn_mfma_f32_16x16x32_bf16(
                    a[m], b[n], acc3[m][n], 0, 0, 0);
    }
    __syncthreads();   // everyone done READING h2 before f32 overwrite
    #pragma unroll
    for (int n = 0; n < 2; ++n) {
        int col = wn * 32 + n * 16 + l15;
        float bias = b3[col];
        #pragma unroll
        for (int m = 0; m < 4; ++m)
            #pragma unroll
            for (int r = 0; r < 4; ++r) {
                int row = wm * 64 + m * 16 + lhi * 4 + r;
                float v = lrelu(acc3[m][n][r] + bias);
                *reinterpret_cast<float*>(
                    &hs[row * 512 + ((col * 4) ^ ((row & 7) << 4))]) = v;
            }
    }
    __syncthreads();

    // ====================== LayerNorm(128) + store ==========================
    {
        const int row = tid >> 2;   // 0..127
        const int sub = tid & 3;    // 4 lanes per row (consecutive -> shfl_xor 1,2)
        f32x4 vv[8];
        float s = 0.f, s2 = 0.f;
        #pragma unroll
        for (int j = 0; j < 8; ++j) {
            int cb = j * 16 + sub * 4;
            f32x4 t = *reinterpret_cast<const f32x4*>(
                &hs[row * 512 + ((cb * 4) ^ ((row & 7) << 4))]);
            vv[j] = t;
            s  += t.x + t.y + t.z + t.w;
            s2 += t.x * t.x + t.y * t.y + t.z * t.z + t.w * t.w;
        }
        s  += __shfl_xor(s, 1);  s  += __shfl_xor(s, 2);
        s2 += __shfl_xor(s2, 1); s2 += __shfl_xor(s2, 2);
        const float mean = s * (1.f / 128.f);
        const float var  = s2 * (1.f / 128.f) - mean * mean;
        const float rstd = rsqrtf(var + 1e-5f);
        const int rg = m0 + row;
        if (rg < E) {
            float* op = out + (size_t)rg * 128;
            #pragma unroll
            for (int j = 0; j < 8; ++j) {
                int cb = j * 16 + sub * 4;
                f32x4 g  = *reinterpret_cast<const f32x4*>(gamma + cb);
                f32x4 be = *reinterpret_cast<const f32x4*>(beta + cb);
                f32x4 o;
                o.x = (vv[j].x - mean) * rstd * g.x + be.x;
                o.y = (vv[j].y - mean) * rstd * g.y + be.y;
                o.z = (vv[j].z - mean) * rstd * g.z + be.z;
                o.w = (vv[j].w - mean) * rstd * g.w + be.w;
                *reinterpret_cast<f32x4*>(op + cb) = o;
            }
        }
    }
}

extern "C" void kernel_launch(void* const* d_in, const int* in_sizes, int n_in,
                              void* d_out, int out_size, void* d_ws, size_t ws_size,
                              hipStream_t stream) {
    const float* src  = (const float*)d_in[0];
    const float* dst  = (const float*)d_in[1];
    const float* ea   = (const float*)d_in[2];
    const float* u    = (const float*)d_in[3];
    const int*   bat  = (const int*)d_in[4];
    const float* W1   = (const float*)d_in[5];
    const float* b1   = (const float*)d_in[6];
    const float* W2   = (const float*)d_in[7];
    const float* b2   = (const float*)d_in[8];
    const float* W3   = (const float*)d_in[9];
    const float* b3   = (const float*)d_in[10];
    const float* gam  = (const float*)d_in[11];
    const float* bet  = (const float*)d_in[12];
    float* out = (float*)d_out;
    unsigned short* Wp = (unsigned short*)d_ws;   // 458752 B used

    const int E = in_sizes[0] / 128;

    prep_pack<<<896, 256, 0, stream>>>(W1, W2, W3, Wp);
    const int nblk = (E + 127) / 128;
    edge_mlp<<<nblk, 512, 0, stream>>>(src, dst, ea, u, bat, Wp,
                                       b1, b2, b3, gam, bet, out, E);
}